// Round 1
// baseline (1306.814 us; speedup 1.0000x reference)
//
#include <hip/hip_runtime.h>
#include <math.h>

// Problem constants
constexpr int NROI = 2048;  // N
constexpr int CDIM = 1024;  // C
constexpr int NG   = 16;    // groups
constexpr int DH   = 64;    // per-group dim

// ---------------- Tiled fp32 NT-GEMM: Cm = act(A) @ W^T + bias ----------------
// A: (M,K) row-major, W: (Nn,K) row-major, Cm: (M,Nn)
constexpr int GTM = 64;
constexpr int GTN = 64;
constexpr int GTK = 16;

__global__ __launch_bounds__(256) void gemm_nt(
    const float* __restrict__ A,
    const float* __restrict__ W,
    const float* __restrict__ bias,   // nullptr for none
    float* __restrict__ Cm,
    int M, int Nn, int K, int doRelu)
{
  __shared__ float As[GTM][GTK + 1];  // pad 17: conflict-free reads (17 coprime 32)
  __shared__ float Ws[GTN][GTK + 1];
  const int t  = threadIdx.x;
  const int tx = t & 15;   // 4 cols each
  const int ty = t >> 4;   // 4 rows each
  const int row0 = blockIdx.y * GTM;
  const int col0 = blockIdx.x * GTN;
  const int lr = t >> 2;        // loader row 0..63
  const int lk = (t & 3) * 4;   // loader k quad

  float acc[4][4] = {};

  for (int k0 = 0; k0 < K; k0 += GTK) {
    float4 av = *(const float4*)(A + (size_t)(row0 + lr) * K + k0 + lk);
    if (doRelu) {
      av.x = fmaxf(av.x, 0.f); av.y = fmaxf(av.y, 0.f);
      av.z = fmaxf(av.z, 0.f); av.w = fmaxf(av.w, 0.f);
    }
    As[lr][lk + 0] = av.x; As[lr][lk + 1] = av.y;
    As[lr][lk + 2] = av.z; As[lr][lk + 3] = av.w;
    float4 wv = *(const float4*)(W + (size_t)(col0 + lr) * K + k0 + lk);
    Ws[lr][lk + 0] = wv.x; Ws[lr][lk + 1] = wv.y;
    Ws[lr][lk + 2] = wv.z; Ws[lr][lk + 3] = wv.w;
    __syncthreads();
#pragma unroll
    for (int kk = 0; kk < GTK; ++kk) {
      const float a0 = As[ty * 4 + 0][kk], a1 = As[ty * 4 + 1][kk],
                  a2 = As[ty * 4 + 2][kk], a3 = As[ty * 4 + 3][kk];
      const float w0 = Ws[tx * 4 + 0][kk], w1 = Ws[tx * 4 + 1][kk],
                  w2 = Ws[tx * 4 + 2][kk], w3 = Ws[tx * 4 + 3][kk];
      acc[0][0] += a0 * w0; acc[0][1] += a0 * w1; acc[0][2] += a0 * w2; acc[0][3] += a0 * w3;
      acc[1][0] += a1 * w0; acc[1][1] += a1 * w1; acc[1][2] += a1 * w2; acc[1][3] += a1 * w3;
      acc[2][0] += a2 * w0; acc[2][1] += a2 * w1; acc[2][2] += a2 * w2; acc[2][3] += a2 * w3;
      acc[3][0] += a3 * w0; acc[3][1] += a3 * w1; acc[3][2] += a3 * w2; acc[3][3] += a3 * w3;
    }
    __syncthreads();
  }

  float4 bv = make_float4(0.f, 0.f, 0.f, 0.f);
  if (bias) bv = *(const float4*)(bias + col0 + tx * 4);
#pragma unroll
  for (int i = 0; i < 4; ++i) {
    float4 o;
    o.x = acc[i][0] + bv.x; o.y = acc[i][1] + bv.y;
    o.z = acc[i][2] + bv.z; o.w = acc[i][3] + bv.w;
    *(float4*)(Cm + (size_t)(row0 + ty * 4 + i) * Nn + col0 + tx * 4) = o;
  }
}

// ---------------- Flash attention over groups, bias = log(iou+1e-6) inline ----------------
// X: (N,C) embedded (Q and K), Zv: (N,C) pre-projected V (= in_x @ Wout^T),
// Out[n, g*64+o] = sum_m softmax_m(QK/8 + log(iou+1e-6)) * Zv[m, g*64+o] + bout
constexpr int BM = 32;  // query rows per block
constexpr int BN = 32;  // key tile

__global__ __launch_bounds__(256) void attn_kernel(
    const float* __restrict__ X,
    const float* __restrict__ Zv,
    const float* __restrict__ rois,   // (N,5): [b, x1,y1,x2,y2]
    const float* __restrict__ bout,   // (C)
    float* __restrict__ Out)          // (N,C)
{
  const int g  = blockIdx.y;
  const int n0 = blockIdx.x * BM;
  const int t  = threadIdx.x;
  const int si  = t & 31;          // S row / acc row
  const int sj0 = (t >> 5) * 4;    // 4 S cols per thread
  const int ad  = (t >> 5) * 8;    // 8 acc dims per thread

  __shared__ float Ks[BN][DH + 4]; // pad 4: float4-aligned rows, banks shift by 4/row
  __shared__ float Vs[BN][DH + 4];
  __shared__ float Ss[BM][BN + 1];
  __shared__ float Bs[BN][5];      // x1,y1,x2,y2,area for key boxes
  __shared__ float mrow[BM], lrow[BM], arow[BM];

  // Q row into registers (64 floats)
  float4 q[16];
  {
    const float* qp = X + (size_t)(n0 + si) * CDIM + g * DH;
#pragma unroll
    for (int d4 = 0; d4 < 16; ++d4) q[d4] = ((const float4*)qp)[d4];
  }
  // query box
  const float* rb = rois + (size_t)(n0 + si) * 5;
  const float rx1 = rb[1], ry1 = rb[2], rx2 = rb[3], ry2 = rb[4];
  const float rarea = (rx2 - rx1 + 1.f) * (ry2 - ry1 + 1.f);

  float acc[8] = {};
  if (t < BM) { mrow[t] = -1e30f; lrow[t] = 0.f; }

  for (int m0 = 0; m0 < NROI; m0 += BN) {
    __syncthreads();  // guard LDS reuse from previous iteration
    {
      const int r = t >> 3;
      const int c = (t & 7) * 8;
      const float* kp = X  + (size_t)(m0 + r) * CDIM + g * DH + c;
      const float* vp = Zv + (size_t)(m0 + r) * CDIM + g * DH + c;
      const float4 k0 = ((const float4*)kp)[0], k1 = ((const float4*)kp)[1];
      const float4 v0 = ((const float4*)vp)[0], v1 = ((const float4*)vp)[1];
      *(float4*)&Ks[r][c] = k0; *(float4*)&Ks[r][c + 4] = k1;
      *(float4*)&Vs[r][c] = v0; *(float4*)&Vs[r][c + 4] = v1;
      if (t < BN) {
        const float* cb = rois + (size_t)(m0 + t) * 5;
        const float x1 = cb[1], y1 = cb[2], x2 = cb[3], y2 = cb[4];
        Bs[t][0] = x1; Bs[t][1] = y1; Bs[t][2] = x2; Bs[t][3] = y2;
        Bs[t][4] = (x2 - x1 + 1.f) * (y2 - y1 + 1.f);
      }
    }
    __syncthreads();

    // S = QK^T/8 + log(iou+1e-6)
    float sv[4];
#pragma unroll
    for (int j = 0; j < 4; ++j) {
      const int jj = sj0 + j;
      const float4* kr = (const float4*)&Ks[jj][0];
      float s0 = 0.f, s1 = 0.f, s2 = 0.f, s3 = 0.f;
#pragma unroll
      for (int d4 = 0; d4 < 16; d4 += 4) {
        const float4 k0 = kr[d4], k1 = kr[d4 + 1], k2 = kr[d4 + 2], k3 = kr[d4 + 3];
        s0 += q[d4    ].x * k0.x + q[d4    ].y * k0.y + q[d4    ].z * k0.z + q[d4    ].w * k0.w;
        s1 += q[d4 + 1].x * k1.x + q[d4 + 1].y * k1.y + q[d4 + 1].z * k1.z + q[d4 + 1].w * k1.w;
        s2 += q[d4 + 2].x * k2.x + q[d4 + 2].y * k2.y + q[d4 + 2].z * k2.z + q[d4 + 2].w * k2.w;
        s3 += q[d4 + 3].x * k3.x + q[d4 + 3].y * k3.y + q[d4 + 3].z * k3.z + q[d4 + 3].w * k3.w;
      }
      const float s = (s0 + s1 + s2 + s3) * 0.125f;
      float iw = fminf(rx2, Bs[jj][2]) - fmaxf(rx1, Bs[jj][0]) + 1.f;
      float ih = fminf(ry2, Bs[jj][3]) - fmaxf(ry1, Bs[jj][1]) + 1.f;
      iw = fmaxf(iw, 0.f); ih = fmaxf(ih, 0.f);
      const float inter = iw * ih;
      const float iou = inter / (rarea + Bs[jj][4] - inter);
      sv[j] = s + __logf(iou + 1e-6f);
      Ss[si][jj] = sv[j];
    }
    __syncthreads();

    // per-row running max + rescale factor
    if (t < BM) {
      float tm = -1e30f;
#pragma unroll
      for (int j = 0; j < BN; ++j) tm = fmaxf(tm, Ss[t][j]);
      const float nm = fmaxf(mrow[t], tm);
      arow[t] = __expf(mrow[t] - nm);
      mrow[t] = nm;
    }
    __syncthreads();

    // P = exp(S - m_new)
#pragma unroll
    for (int j = 0; j < 4; ++j) Ss[si][sj0 + j] = __expf(sv[j] - mrow[si]);
    __syncthreads();

    // row sums (row threads) + PV accumulate (all threads)
    if (t < BM) {
      float rs = 0.f;
#pragma unroll
      for (int j = 0; j < BN; ++j) rs += Ss[t][j];
      lrow[t] = lrow[t] * arow[t] + rs;
    }
    const float al = arow[si];
#pragma unroll
    for (int dd = 0; dd < 8; ++dd) acc[dd] *= al;
#pragma unroll
    for (int j = 0; j < BN; ++j) {
      const float pv = Ss[si][j];
      const float4 v0 = *(const float4*)&Vs[j][ad];
      const float4 v1 = *(const float4*)&Vs[j][ad + 4];
      acc[0] += pv * v0.x; acc[1] += pv * v0.y; acc[2] += pv * v0.z; acc[3] += pv * v0.w;
      acc[4] += pv * v1.x; acc[5] += pv * v1.y; acc[6] += pv * v1.z; acc[7] += pv * v1.w;
    }
  }
  __syncthreads();

  const float linv = 1.f / lrow[si];
  const float* bo = bout + g * DH + ad;
  float* op = Out + (size_t)(n0 + si) * CDIM + g * DH + ad;
  float4 o0, o1;
  o0.x = acc[0] * linv + bo[0]; o0.y = acc[1] * linv + bo[1];
  o0.z = acc[2] * linv + bo[2]; o0.w = acc[3] * linv + bo[3];
  o1.x = acc[4] * linv + bo[4]; o1.y = acc[5] * linv + bo[5];
  o1.z = acc[6] * linv + bo[6]; o1.w = acc[7] * linv + bo[7];
  *(float4*)op = o0; *(float4*)(op + 4) = o1;
}

extern "C" void kernel_launch(void* const* d_in, const int* in_sizes, int n_in,
                              void* d_out, int out_size, void* d_ws, size_t ws_size,
                              hipStream_t stream) {
  const float* in_x = (const float*)d_in[0];
  const float* rois = (const float*)d_in[1];
  const float* W0   = (const float*)d_in[2];
  const float* b0   = (const float*)d_in[3];
  const float* W1   = (const float*)d_in[4];
  const float* b1   = (const float*)d_in[5];
  const float* Wout = (const float*)d_in[6];  // (G,D,C) flat == (C,C) row-major
  const float* bout = (const float*)d_in[7];
  float* out = (float*)d_out;
  float* ws  = (float*)d_ws;

  // ws layout (16 MB): bufA = embedded x; bufB = GEMM1 temp, then reused for Z
  float* bufA = ws;
  float* bufB = ws + (size_t)NROI * CDIM;

  const dim3 gg(CDIM / GTN, NROI / GTM);  // (16, 32) = 512 blocks
  // tmp = relu(in_x) @ W0^T + b0
  gemm_nt<<<gg, 256, 0, stream>>>(in_x, W0, b0, bufB, NROI, CDIM, CDIM, 1);
  // x   = relu(tmp)  @ W1^T + b1
  gemm_nt<<<gg, 256, 0, stream>>>(bufB, W1, b1, bufA, NROI, CDIM, CDIM, 1);
  // Z   = in_x @ Wout^T   (linearity: out = attn @ (in_x @ Wout^T) + bout)
  gemm_nt<<<gg, 256, 0, stream>>>(in_x, Wout, nullptr, bufB, NROI, CDIM, CDIM, 0);
  // flash attention per (n-tile, group), bias computed inline from rois
  attn_kernel<<<dim3(NROI / BM, NG), 256, 0, stream>>>(bufA, bufB, rois, bout, out);
}

// Round 2
// 554.101 us; speedup vs baseline: 2.3584x; 2.3584x over previous
//
#include <hip/hip_runtime.h>
#include <math.h>

// Problem constants
constexpr int NROI = 2048;  // N
constexpr int CDIM = 1024;  // C
constexpr int NG   = 16;    // groups
constexpr int DH   = 64;    // per-group dim

typedef __attribute__((ext_vector_type(8))) short short8;    // 8 bf16 (4 VGPRs)
typedef __attribute__((ext_vector_type(4))) float floatx4;   // MFMA C/D frag

#define MFMA_BF16(a, b, c) __builtin_amdgcn_mfma_f32_16x16x32_bf16((a), (b), (c), 0, 0, 0)

// fp32 -> bf16 round-to-nearest-even (avoids header-API drift)
__device__ __forceinline__ short f2bf(float f) {
  unsigned u = __float_as_uint(f);
  unsigned r = 0x7fffu + ((u >> 16) & 1u);
  return (short)((u + r) >> 16);
}

// ---------------- Tiled fp32 NT-GEMM: C = act(A) @ W^T + bias ----------------
// outMode: 0 = fp32 row-major, 1 = bf16 row-major, 2 = bf16 TRANSPOSED (Nn x M)
constexpr int GTM = 64;
constexpr int GTN = 64;
constexpr int GTK = 16;

__global__ __launch_bounds__(256) void gemm_nt(
    const float* __restrict__ A,
    const float* __restrict__ W,
    const float* __restrict__ bias,
    float* __restrict__ Cf, short* __restrict__ Cb, short* __restrict__ CbT,
    int M, int Nn, int K, int doRelu, int outMode)
{
  __shared__ float As[GTM][GTK + 1];
  __shared__ float Ws[GTN][GTK + 1];
  const int t  = threadIdx.x;
  const int tx = t & 15;
  const int ty = t >> 4;
  const int row0 = blockIdx.y * GTM;
  const int col0 = blockIdx.x * GTN;
  const int lr = t >> 2;
  const int lk = (t & 3) * 4;

  float acc[4][4] = {};

  for (int k0 = 0; k0 < K; k0 += GTK) {
    float4 av = *(const float4*)(A + (size_t)(row0 + lr) * K + k0 + lk);
    if (doRelu) {
      av.x = fmaxf(av.x, 0.f); av.y = fmaxf(av.y, 0.f);
      av.z = fmaxf(av.z, 0.f); av.w = fmaxf(av.w, 0.f);
    }
    As[lr][lk + 0] = av.x; As[lr][lk + 1] = av.y;
    As[lr][lk + 2] = av.z; As[lr][lk + 3] = av.w;
    float4 wv = *(const float4*)(W + (size_t)(col0 + lr) * K + k0 + lk);
    Ws[lr][lk + 0] = wv.x; Ws[lr][lk + 1] = wv.y;
    Ws[lr][lk + 2] = wv.z; Ws[lr][lk + 3] = wv.w;
    __syncthreads();
#pragma unroll
    for (int kk = 0; kk < GTK; ++kk) {
      const float a0 = As[ty * 4 + 0][kk], a1 = As[ty * 4 + 1][kk],
                  a2 = As[ty * 4 + 2][kk], a3 = As[ty * 4 + 3][kk];
      const float w0 = Ws[tx * 4 + 0][kk], w1 = Ws[tx * 4 + 1][kk],
                  w2 = Ws[tx * 4 + 2][kk], w3 = Ws[tx * 4 + 3][kk];
      acc[0][0] += a0 * w0; acc[0][1] += a0 * w1; acc[0][2] += a0 * w2; acc[0][3] += a0 * w3;
      acc[1][0] += a1 * w0; acc[1][1] += a1 * w1; acc[1][2] += a1 * w2; acc[1][3] += a1 * w3;
      acc[2][0] += a2 * w0; acc[2][1] += a2 * w1; acc[2][2] += a2 * w2; acc[2][3] += a2 * w3;
      acc[3][0] += a3 * w0; acc[3][1] += a3 * w1; acc[3][2] += a3 * w2; acc[3][3] += a3 * w3;
    }
    __syncthreads();
  }

  float bv[4] = {0.f, 0.f, 0.f, 0.f};
  if (bias) {
    float4 b4 = *(const float4*)(bias + col0 + tx * 4);
    bv[0] = b4.x; bv[1] = b4.y; bv[2] = b4.z; bv[3] = b4.w;
  }

  if (outMode == 0) {
#pragma unroll
    for (int i = 0; i < 4; ++i) {
      float4 o;
      o.x = acc[i][0] + bv[0]; o.y = acc[i][1] + bv[1];
      o.z = acc[i][2] + bv[2]; o.w = acc[i][3] + bv[3];
      *(float4*)(Cf + (size_t)(row0 + ty * 4 + i) * Nn + col0 + tx * 4) = o;
    }
  } else if (outMode == 1) {
#pragma unroll
    for (int i = 0; i < 4; ++i) {
      unsigned long long u = 0;
#pragma unroll
      for (int j = 0; j < 4; ++j)
        u |= ((unsigned long long)(unsigned short)f2bf(acc[i][j] + bv[j])) << (16 * j);
      *(unsigned long long*)(Cb + (size_t)(row0 + ty * 4 + i) * Nn + col0 + tx * 4) = u;
    }
  } else {
    // transposed bf16: CbT[col][row], rows ty*4..+3 contiguous
#pragma unroll
    for (int j = 0; j < 4; ++j) {
      unsigned long long u = 0;
#pragma unroll
      for (int i = 0; i < 4; ++i)
        u |= ((unsigned long long)(unsigned short)f2bf(acc[i][j] + bv[j])) << (16 * i);
      *(unsigned long long*)(CbT + (size_t)(col0 + tx * 4 + j) * M + row0 + ty * 4) = u;
    }
  }
}

// ---------------- MFMA flash attention ----------------
// Xb:  (N,C) bf16 embedded x (Q and K). ZTb: (C,N) bf16 projected V, transposed.
// Block: 64 q-rows x 1 group, 4 waves (16 q-rows each). 64-key iterations.
// LDS frag-major layout: frag slot = frag*512 + lane*8 shorts -> all frag
// reads are contiguous per-wave ds_read_b128 (identity pattern, conflict-free).
__global__ __launch_bounds__(256) void attn_mfma(
    const short* __restrict__ Xb,
    const short* __restrict__ ZTb,
    const float* __restrict__ rois,
    const float* __restrict__ bout,
    float* __restrict__ Out)
{
  const int g    = blockIdx.y;
  const int n0   = blockIdx.x * 64;
  const int t    = threadIdx.x;
  const int w    = t >> 6;
  const int lane = t & 63;
  const int col  = lane & 15;   // C-frag col / A-frag m
  const int qq   = lane >> 4;   // C-frag row quad

  __shared__ short Kf[8 * 64 * 8];      // 8 B-frags of K^T (key tiles x k-halves)
  __shared__ short Vf[8 * 64 * 8];      // 8 B-frags of V (dim tiles x key-halves)
  __shared__ short Pf[4 * 2 * 64 * 8];  // per-wave P A-frags (2 key-halves)
  __shared__ float Bs[64 * 5];          // key boxes: x1,y1,x2,y2,area

  // Q A-frags: A[m = lane&15][k = qq*8+j], two k-halves
  const size_t qoff = (size_t)(n0 + w * 16 + col) * CDIM + g * 64;
  const short8 qf0 = *(const short8*)(Xb + qoff + qq * 8);
  const short8 qf1 = *(const short8*)(Xb + qoff + 32 + qq * 8);

  // query boxes for this lane's 4 C-rows
  float qx1[4], qy1[4], qx2[4], qy2[4], qar[4];
#pragma unroll
  for (int r = 0; r < 4; ++r) {
    const float* rb = rois + (size_t)(n0 + w * 16 + qq * 4 + r) * 5;
    qx1[r] = rb[1]; qy1[r] = rb[2]; qx2[r] = rb[3]; qy2[r] = rb[4];
    qar[r] = (qx2[r] - qx1[r] + 1.f) * (qy2[r] - qy1[r] + 1.f);
  }

  floatx4 oc[4];
#pragma unroll
  for (int dt = 0; dt < 4; ++dt) oc[dt] = (floatx4){0.f, 0.f, 0.f, 0.f};
  float mrun[4] = {-1e30f, -1e30f, -1e30f, -1e30f};
  float lrun[4] = {0.f, 0.f, 0.f, 0.f};

  for (int m0 = 0; m0 < NROI; m0 += 64) {
    __syncthreads();  // protect K/V/Bs from previous iteration's readers
    // ---- stage K tile (64 keys x 64 dims) and V tile into frag-major LDS ----
#pragma unroll
    for (int ss = 0; ss < 2; ++ss) {
      const int s = t + ss * 256;        // 512 16B-segments per tile
      {
        const int key = s >> 3, d0 = (s & 7) * 8;
        const int fr = (key >> 4) * 2 + (d0 >> 5);
        const int dl = (key & 15) + ((d0 >> 3) & 3) * 16;
        *(short8*)&Kf[fr * 512 + dl * 8] =
            *(const short8*)(Xb + (size_t)(m0 + key) * CDIM + g * 64 + d0);
      }
      {
        const int d = s >> 3, k0 = (s & 7) * 8;
        const int fr = (d >> 4) * 2 + (k0 >> 5);
        const int dl = (d & 15) + ((k0 >> 3) & 3) * 16;
        *(short8*)&Vf[fr * 512 + dl * 8] =
            *(const short8*)(ZTb + (size_t)(g * 64 + d) * NROI + m0 + k0);
      }
    }
    if (t < 64) {
      const float* rb = rois + (size_t)(m0 + t) * 5;
      const float x1 = rb[1], y1 = rb[2], x2 = rb[3], y2 = rb[4];
      Bs[t * 5 + 0] = x1; Bs[t * 5 + 1] = y1;
      Bs[t * 5 + 2] = x2; Bs[t * 5 + 3] = y2;
      Bs[t * 5 + 4] = (x2 - x1 + 1.f) * (y2 - y1 + 1.f);
    }
    __syncthreads();

    // ---- S = Q K^T (4 key-tiles of 16) ----
    floatx4 sc[4];
#pragma unroll
    for (int ct = 0; ct < 4; ++ct) {
      const short8 b0 = *(const short8*)&Kf[(ct * 2 + 0) * 512 + lane * 8];
      const short8 b1 = *(const short8*)&Kf[(ct * 2 + 1) * 512 + lane * 8];
      floatx4 z4 = (floatx4){0.f, 0.f, 0.f, 0.f};
      z4 = MFMA_BF16(qf0, b0, z4);
      z4 = MFMA_BF16(qf1, b1, z4);
      sc[ct] = z4;
    }

    // ---- scale + iou-log bias (inline) ----
#pragma unroll
    for (int ct = 0; ct < 4; ++ct) {
      const int k = ct * 16 + col;
      const float kx1 = Bs[k * 5 + 0], ky1 = Bs[k * 5 + 1];
      const float kx2 = Bs[k * 5 + 2], ky2 = Bs[k * 5 + 3], ka = Bs[k * 5 + 4];
#pragma unroll
      for (int r = 0; r < 4; ++r) {
        float iw = fminf(qx2[r], kx2) - fmaxf(qx1[r], kx1) + 1.f;
        float ih = fminf(qy2[r], ky2) - fmaxf(qy1[r], ky1) + 1.f;
        iw = fmaxf(iw, 0.f); ih = fmaxf(ih, 0.f);
        const float inter = iw * ih;
        const float iou = inter / (qar[r] + ka - inter);
        sc[ct][r] = sc[ct][r] * 0.125f + __logf(iou + 1e-6f);
      }
    }

    // ---- online softmax (shuffle reductions across the 16 col-lanes) ----
    float mnew[4], alpha[4];
#pragma unroll
    for (int r = 0; r < 4; ++r) {
      float tm = fmaxf(fmaxf(sc[0][r], sc[1][r]), fmaxf(sc[2][r], sc[3][r]));
      tm = fmaxf(tm, __shfl_xor(tm, 1));
      tm = fmaxf(tm, __shfl_xor(tm, 2));
      tm = fmaxf(tm, __shfl_xor(tm, 4));
      tm = fmaxf(tm, __shfl_xor(tm, 8));
      mnew[r] = fmaxf(mrun[r], tm);
      alpha[r] = __expf(mrun[r] - mnew[r]);
      mrun[r] = mnew[r];
    }
#pragma unroll
    for (int ct = 0; ct < 4; ++ct)
#pragma unroll
      for (int r = 0; r < 4; ++r) sc[ct][r] = __expf(sc[ct][r] - mnew[r]);
#pragma unroll
    for (int r = 0; r < 4; ++r) {
      float rs = sc[0][r] + sc[1][r] + sc[2][r] + sc[3][r];
      rs += __shfl_xor(rs, 1);
      rs += __shfl_xor(rs, 2);
      rs += __shfl_xor(rs, 4);
      rs += __shfl_xor(rs, 8);
      lrun[r] = lrun[r] * alpha[r] + rs;
    }
#pragma unroll
    for (int dt = 0; dt < 4; ++dt)
#pragma unroll
      for (int r = 0; r < 4; ++r) oc[dt][r] *= alpha[r];

    // ---- P: C-layout -> A-layout via in-wave LDS roundtrip ----
    {
      short* pw = &Pf[w * 1024];
#pragma unroll
      for (int ct = 0; ct < 4; ++ct) {
        const int key = ct * 16 + col;
        const int h = key >> 5;
        const int base = h * 512 + (key & 7);
#pragma unroll
        for (int r = 0; r < 4; ++r) {
          const int dl = (4 * qq + r) + ((key >> 3) & 3) * 16;
          pw[base + dl * 8] = f2bf(sc[ct][r]);
        }
      }
      const short8 pa0 = *(const short8*)&pw[0 * 512 + lane * 8];
      const short8 pa1 = *(const short8*)&pw[1 * 512 + lane * 8];
      // ---- O += P V ----
#pragma unroll
      for (int dt = 0; dt < 4; ++dt) {
        const short8 v0 = *(const short8*)&Vf[(dt * 2 + 0) * 512 + lane * 8];
        const short8 v1 = *(const short8*)&Vf[(dt * 2 + 1) * 512 + lane * 8];
        oc[dt] = MFMA_BF16(pa0, v0, oc[dt]);
        oc[dt] = MFMA_BF16(pa1, v1, oc[dt]);
      }
    }
  }

  // ---- epilogue: normalize, + bout ----
#pragma unroll
  for (int dt = 0; dt < 4; ++dt) {
    const float bo = bout[g * 64 + dt * 16 + col];
#pragma unroll
    for (int r = 0; r < 4; ++r) {
      Out[(size_t)(n0 + w * 16 + qq * 4 + r) * CDIM + g * 64 + dt * 16 + col] =
          oc[dt][r] / lrun[r] + bo;
    }
  }
}

extern "C" void kernel_launch(void* const* d_in, const int* in_sizes, int n_in,
                              void* d_out, int out_size, void* d_ws, size_t ws_size,
                              hipStream_t stream) {
  const float* in_x = (const float*)d_in[0];
  const float* rois = (const float*)d_in[1];
  const float* W0   = (const float*)d_in[2];
  const float* b0   = (const float*)d_in[3];
  const float* W1   = (const float*)d_in[4];
  const float* b1   = (const float*)d_in[5];
  const float* Wout = (const float*)d_in[6];  // (G,D,C) flat == (C,C) row-major
  const float* bout = (const float*)d_in[7];
  float* out = (float*)d_out;
  float* ws  = (float*)d_ws;

  // ws layout (16 MB total): tmp fp32 8MB | x bf16 4MB | zT bf16 4MB
  float* tmp = ws;
  short* xb  = (short*)(ws + (size_t)NROI * CDIM);
  short* zT  = xb + (size_t)NROI * CDIM;

  const dim3 gg(CDIM / GTN, NROI / GTM);
  // tmp = relu(in_x) @ W0^T + b0   (fp32)
  gemm_nt<<<gg, 256, 0, stream>>>(in_x, W0, b0, tmp, nullptr, nullptr,
                                  NROI, CDIM, CDIM, 1, 0);
  // xb  = bf16( relu(tmp) @ W1^T + b1 )
  gemm_nt<<<gg, 256, 0, stream>>>(tmp, W1, b1, nullptr, xb, nullptr,
                                  NROI, CDIM, CDIM, 1, 1);
  // zT  = bf16( in_x @ Wout^T )^T   (C x N)
  gemm_nt<<<gg, 256, 0, stream>>>(in_x, Wout, nullptr, nullptr, nullptr, zT,
                                  NROI, CDIM, CDIM, 0, 2);
  // MFMA flash attention with inline iou-log bias
  attn_mfma<<<dim3(NROI / 64, NG), 256, 0, stream>>>(xb, zT, rois, bout, out);
}

// Round 3
// 200.233 us; speedup vs baseline: 6.5265x; 2.7673x over previous
//
#include <hip/hip_runtime.h>
#include <math.h>

// Problem constants
constexpr int NROI = 2048;  // N
constexpr int CDIM = 1024;  // C
constexpr int NG   = 16;    // groups
constexpr int DH   = 64;    // per-group dim

typedef __attribute__((ext_vector_type(8))) short short8;    // 8 bf16 (4 VGPRs)
typedef __attribute__((ext_vector_type(4))) float floatx4;   // MFMA C/D frag

#define MFMA_BF16(a, b, c) __builtin_amdgcn_mfma_f32_16x16x32_bf16((a), (b), (c), 0, 0, 0)

// fp32 -> bf16 round-to-nearest-even
__device__ __forceinline__ short f2bf(float f) {
  unsigned u = __float_as_uint(f);
  unsigned r = 0x7fffu + ((u >> 16) & 1u);
  return (short)((u + r) >> 16);
}
__device__ __forceinline__ float bf2f(unsigned short u) {
  return __uint_as_float(((unsigned)u) << 16);
}
__device__ __forceinline__ unsigned pack2(float a, float b) {
  return (unsigned)(unsigned short)f2bf(a) | ((unsigned)(unsigned short)f2bf(b) << 16);
}

// async global->LDS, 16B per lane; LDS dest = wave-uniform base + lane*16
typedef __attribute__((address_space(1))) void GV;
typedef __attribute__((address_space(3))) void LV;
__device__ __forceinline__ void gl2lds16(const void* g, void* l) {
  __builtin_amdgcn_global_load_lds((GV*)g, (LV*)l, 16, 0, 0);
}

// bf16 relu on a packed short8 (sign-bit based; exact)
__device__ __forceinline__ short8 brelu(short8 v) {
  union { short8 s; unsigned u[4]; } x; x.s = v;
#pragma unroll
  for (int i = 0; i < 4; ++i) {
    unsigned m = (x.u[i] >> 15) & 0x10001u;   // sign bit of each bf16 half
    x.u[i] &= ~(m * 0xFFFFu);                 // zero negative halves
  }
  return x.s;
}

// ---------------- conversion: fp32 -> bf16 for activations & weights ----------------
__global__ __launch_bounds__(256) void convert_kernel(
    const float* __restrict__ in_x, const float* __restrict__ W0,
    const float* __restrict__ W1, const float* __restrict__ Wout,
    short* __restrict__ xin_b, short* __restrict__ W0b,
    short* __restrict__ W1b, short* __restrict__ Woutb)
{
  const int i = blockIdx.x * 256 + threadIdx.x;     // 0..524287 (float4 units)
  {
    const float4 v = ((const float4*)in_x)[i];
    uint2 u; u.x = pack2(v.x, v.y); u.y = pack2(v.z, v.w);
    ((uint2*)xin_b)[i] = u;
  }
  if (i < 262144) {
    float4 v = ((const float4*)W0)[i];
    uint2 u; u.x = pack2(v.x, v.y); u.y = pack2(v.z, v.w);
    ((uint2*)W0b)[i] = u;
    v = ((const float4*)W1)[i];
    u.x = pack2(v.x, v.y); u.y = pack2(v.z, v.w);
    ((uint2*)W1b)[i] = u;
    v = ((const float4*)Wout)[i];
    u.x = pack2(v.x, v.y); u.y = pack2(v.z, v.w);
    ((uint2*)Woutb)[i] = u;
  }
}

// ---------------- iou+1e-6 matrix (bf16), g-independent attention bias ----------------
__global__ __launch_bounds__(256) void iou_kernel(const float* __restrict__ rois,
                                                  unsigned short* __restrict__ biasb)
{
  const int q = blockIdx.y;
  const int k = blockIdx.x * 256 + threadIdx.x;
  const float qx1 = rois[q * 5 + 1], qy1 = rois[q * 5 + 2];
  const float qx2 = rois[q * 5 + 3], qy2 = rois[q * 5 + 4];
  const float qa = (qx2 - qx1 + 1.f) * (qy2 - qy1 + 1.f);
  const float kx1 = rois[k * 5 + 1], ky1 = rois[k * 5 + 2];
  const float kx2 = rois[k * 5 + 3], ky2 = rois[k * 5 + 4];
  const float ka = (kx2 - kx1 + 1.f) * (ky2 - ky1 + 1.f);
  float iw = fminf(qx2, kx2) - fmaxf(qx1, kx1) + 1.f;
  float ih = fminf(qy2, ky2) - fmaxf(qy1, ky1) + 1.f;
  iw = fmaxf(iw, 0.f); ih = fmaxf(ih, 0.f);
  const float inter = iw * ih;
  const float iou = inter / (qa + ka - inter);
  biasb[(size_t)q * NROI + k] = (unsigned short)f2bf(iou + 1e-6f);
}

// ---------------- bf16 MFMA NT-GEMM: C = [relu](A) @ B^T + bias ----------------
// A:(M,K) bf16 row-major, B:(Nn,K) bf16 row-major. 64x64 tile, BK=64, 4 waves.
// LDS frag-major: frag id = (idx16*2 + khalf), lane l holds row l&15, k (l>>4)*8.
__global__ __launch_bounds__(256) void gemm_bf16(
    const short* __restrict__ A, const short* __restrict__ B,
    const float* __restrict__ bias, short* __restrict__ C,
    int M, int Nn, int K, int reluA, int transOut)
{
  __shared__ short As[8 * 512];
  __shared__ short Bs[8 * 512];
  const int t = threadIdx.x, w = t >> 6, lane = t & 63;
  const int wm = w >> 1, wn = w & 1;
  const int row0 = blockIdx.y * 64, col0 = blockIdx.x * 64;
  const int rlo = lane & 15, khi = (lane >> 4) * 8;

  floatx4 acc[2][2];
#pragma unroll
  for (int i = 0; i < 2; ++i)
#pragma unroll
    for (int j = 0; j < 2; ++j) acc[i][j] = (floatx4){0.f, 0.f, 0.f, 0.f};

  for (int k0 = 0; k0 < K; k0 += 64) {
    __syncthreads();   // all waves done reading previous tile
#pragma unroll
    for (int kh = 0; kh < 2; ++kh) {
      gl2lds16(A + (size_t)(row0 + w * 16 + rlo) * K + k0 + kh * 32 + khi,
               &As[(w * 2 + kh) * 512]);
      gl2lds16(B + (size_t)(col0 + w * 16 + rlo) * K + k0 + kh * 32 + khi,
               &Bs[(w * 2 + kh) * 512]);
    }
    __syncthreads();   // implies vmcnt(0) drain of global_load_lds
#pragma unroll
    for (int kh = 0; kh < 2; ++kh) {
      short8 a0 = *(const short8*)&As[((wm * 2 + 0) * 2 + kh) * 512 + lane * 8];
      short8 a1 = *(const short8*)&As[((wm * 2 + 1) * 2 + kh) * 512 + lane * 8];
      if (reluA) { a0 = brelu(a0); a1 = brelu(a1); }
      const short8 b0 = *(const short8*)&Bs[((wn * 2 + 0) * 2 + kh) * 512 + lane * 8];
      const short8 b1 = *(const short8*)&Bs[((wn * 2 + 1) * 2 + kh) * 512 + lane * 8];
      acc[0][0] = MFMA_BF16(a0, b0, acc[0][0]);
      acc[0][1] = MFMA_BF16(a0, b1, acc[0][1]);
      acc[1][0] = MFMA_BF16(a1, b0, acc[1][0]);
      acc[1][1] = MFMA_BF16(a1, b1, acc[1][1]);
    }
  }

  const int colL = lane & 15, qq = lane >> 4;
  float bj[2] = {0.f, 0.f};
  if (bias) {
    bj[0] = bias[col0 + wn * 32 + colL];
    bj[1] = bias[col0 + wn * 32 + 16 + colL];
  }
#pragma unroll
  for (int i = 0; i < 2; ++i)
#pragma unroll
    for (int j = 0; j < 2; ++j)
#pragma unroll
      for (int r = 0; r < 4; ++r) {
        const int row = row0 + wm * 32 + i * 16 + qq * 4 + r;
        const int cc  = col0 + wn * 32 + j * 16 + colL;
        const short bv = f2bf(acc[i][j][r] + bj[j]);
        if (transOut) C[(size_t)cc * M + row] = bv;
        else          C[(size_t)row * Nn + cc] = bv;
      }
}

// ---------------- MFMA flash attention, precomputed iou bias, no-max softmax ----------------
// P = exp(s/8) * (iou+1e-6)  [== exp(s/8 + log(iou+1e-6))], no running max needed.
// Block: 512 threads (8 waves) = 128 q-rows x 1 group; K/V double-buffered via
// global_load_lds (1 barrier/iter, prefetch overlaps compute).
__global__ __launch_bounds__(512) void attn_bias(
    const short* __restrict__ Xb,           // (N,C) bf16 embedded x
    const short* __restrict__ ZTb,          // (C,N) bf16 V, transposed
    const unsigned short* __restrict__ biasb, // (N,N) bf16 iou+1e-6
    const float* __restrict__ bout,
    float* __restrict__ Out)
{
  const int g  = blockIdx.y;
  const int n0 = blockIdx.x * 128;
  const int t  = threadIdx.x;
  const int w    = t >> 6;
  const int lane = t & 63;
  const int col  = lane & 15;
  const int qq   = lane >> 4;
  const int t16 = (w >> 1) * 16;   // staging: frag id = w
  const int h32 = (w & 1) * 32;
  const int rlo = lane & 15, khi = (lane >> 4) * 8;

  __shared__ short Kf[2][8 * 512];
  __shared__ short Vf[2][8 * 512];
  __shared__ short Pf[8 * 1024];

  const size_t qoff = (size_t)(n0 + w * 16 + col) * CDIM + g * DH;
  const short8 qf0 = *(const short8*)(Xb + qoff + qq * 8);
  const short8 qf1 = *(const short8*)(Xb + qoff + 32 + qq * 8);

  floatx4 oc[4];
#pragma unroll
  for (int dt = 0; dt < 4; ++dt) oc[dt] = (floatx4){0.f, 0.f, 0.f, 0.f};
  float lsum[4] = {0.f, 0.f, 0.f, 0.f};

  // stage tile 0 into buffer 0
  gl2lds16(Xb + (size_t)(t16 + rlo) * CDIM + g * DH + h32 + khi, &Kf[0][w * 512]);
  gl2lds16(ZTb + (size_t)(g * DH + t16 + rlo) * NROI + h32 + khi, &Vf[0][w * 512]);
  __syncthreads();

  for (int it = 0; it < NROI / 64; ++it) {
    const int p  = it & 1;
    const int m0 = it * 64;
    if (it + 1 < NROI / 64) {   // prefetch next tile into other buffer (async)
      const int m1 = m0 + 64;
      gl2lds16(Xb + (size_t)(m1 + t16 + rlo) * CDIM + g * DH + h32 + khi,
               &Kf[1 - p][w * 512]);
      gl2lds16(ZTb + (size_t)(g * DH + t16 + rlo) * NROI + m1 + h32 + khi,
               &Vf[1 - p][w * 512]);
    }

    // bias tile loads (issue early; latency overlapped by QK MFMAs)
    float bb[4][4];
#pragma unroll
    for (int ct = 0; ct < 4; ++ct)
#pragma unroll
      for (int r = 0; r < 4; ++r)
        bb[ct][r] = bf2f(biasb[(size_t)(n0 + w * 16 + qq * 4 + r) * NROI +
                               m0 + ct * 16 + col]);

    // S = Q K^T
    floatx4 sc[4];
#pragma unroll
    for (int ct = 0; ct < 4; ++ct) {
      const short8 b0 = *(const short8*)&Kf[p][(ct * 2 + 0) * 512 + lane * 8];
      const short8 b1 = *(const short8*)&Kf[p][(ct * 2 + 1) * 512 + lane * 8];
      floatx4 z4 = (floatx4){0.f, 0.f, 0.f, 0.f};
      z4 = MFMA_BF16(qf0, b0, z4);
      z4 = MFMA_BF16(qf1, b1, z4);
      sc[ct] = z4;
    }

    // P = exp(s/8) * (iou+1e-6); accumulate row sums per-lane (reduced at end)
#pragma unroll
    for (int ct = 0; ct < 4; ++ct)
#pragma unroll
      for (int r = 0; r < 4; ++r)
        sc[ct][r] = __expf(sc[ct][r] * 0.125f) * bb[ct][r];
#pragma unroll
    for (int r = 0; r < 4; ++r)
      lsum[r] += sc[0][r] + sc[1][r] + sc[2][r] + sc[3][r];

    // P: C-layout -> A-layout via wave-private LDS roundtrip
    {
      short* pw = &Pf[w * 1024];
#pragma unroll
      for (int ct = 0; ct < 4; ++ct) {
        const int key = ct * 16 + col;
        const int base = (key >> 5) * 512 + (key & 7);
#pragma unroll
        for (int r = 0; r < 4; ++r) {
          const int dl = (4 * qq + r) + ((key >> 3) & 3) * 16;
          pw[base + dl * 8] = f2bf(sc[ct][r]);
        }
      }
      const short8 pa0 = *(const short8*)&pw[0 * 512 + lane * 8];
      const short8 pa1 = *(const short8*)&pw[1 * 512 + lane * 8];
#pragma unroll
      for (int dt = 0; dt < 4; ++dt) {
        const short8 v0 = *(const short8*)&Vf[p][(dt * 2 + 0) * 512 + lane * 8];
        const short8 v1 = *(const short8*)&Vf[p][(dt * 2 + 1) * 512 + lane * 8];
        oc[dt] = MFMA_BF16(pa0, v0, oc[dt]);
        oc[dt] = MFMA_BF16(pa1, v1, oc[dt]);
      }
    }
    __syncthreads();  // compute(p) done everywhere; drains prefetch into 1-p
  }

  // reduce row sums across the 16 col-lanes
#pragma unroll
  for (int r = 0; r < 4; ++r) {
    float s = lsum[r];
    s += __shfl_xor(s, 1); s += __shfl_xor(s, 2);
    s += __shfl_xor(s, 4); s += __shfl_xor(s, 8);
    lsum[r] = s;
  }
#pragma unroll
  for (int dt = 0; dt < 4; ++dt) {
    const float bo = bout[g * DH + dt * 16 + col];
#pragma unroll
    for (int r = 0; r < 4; ++r)
      Out[(size_t)(n0 + w * 16 + qq * 4 + r) * CDIM + g * DH + dt * 16 + col] =
          oc[dt][r] / lsum[r] + bo;
  }
}

// ---------------- fallback attention (inline iou, no bias matrix; 14 MiB ws) ----------------
__global__ __launch_bounds__(256) void attn_inline(
    const short* __restrict__ Xb, const short* __restrict__ ZTb,
    const float* __restrict__ rois, const float* __restrict__ bout,
    float* __restrict__ Out)
{
  const int g = blockIdx.y, n0 = blockIdx.x * 64;
  const int t = threadIdx.x, w = t >> 6, lane = t & 63;
  const int col = lane & 15, qq = lane >> 4;

  __shared__ short Kf[8 * 512];
  __shared__ short Vf[8 * 512];
  __shared__ short Pf[4 * 1024];
  __shared__ float Bsb[64 * 5];

  const size_t qoff = (size_t)(n0 + w * 16 + col) * CDIM + g * DH;
  const short8 qf0 = *(const short8*)(Xb + qoff + qq * 8);
  const short8 qf1 = *(const short8*)(Xb + qoff + 32 + qq * 8);

  float qx1[4], qy1[4], qx2[4], qy2[4], qar[4];
#pragma unroll
  for (int r = 0; r < 4; ++r) {
    const float* rb = rois + (size_t)(n0 + w * 16 + qq * 4 + r) * 5;
    qx1[r] = rb[1]; qy1[r] = rb[2]; qx2[r] = rb[3]; qy2[r] = rb[4];
    qar[r] = (qx2[r] - qx1[r] + 1.f) * (qy2[r] - qy1[r] + 1.f);
  }

  floatx4 oc[4];
#pragma unroll
  for (int dt = 0; dt < 4; ++dt) oc[dt] = (floatx4){0.f, 0.f, 0.f, 0.f};
  float lsum[4] = {0.f, 0.f, 0.f, 0.f};

  for (int m0 = 0; m0 < NROI; m0 += 64) {
    __syncthreads();
#pragma unroll
    for (int ss = 0; ss < 2; ++ss) {
      const int s = t + ss * 256;
      {
        const int key = s >> 3, d0 = (s & 7) * 8;
        const int fr = (key >> 4) * 2 + (d0 >> 5);
        const int dl = (key & 15) + ((d0 >> 3) & 3) * 16;
        *(short8*)&Kf[fr * 512 + dl * 8] =
            *(const short8*)(Xb + (size_t)(m0 + key) * CDIM + g * DH + d0);
      }
      {
        const int d = s >> 3, k0 = (s & 7) * 8;
        const int fr = (d >> 4) * 2 + (k0 >> 5);
        const int dl = (d & 15) + ((k0 >> 3) & 3) * 16;
        *(short8*)&Vf[fr * 512 + dl * 8] =
            *(const short8*)(ZTb + (size_t)(g * DH + d) * NROI + m0 + k0);
      }
    }
    if (t < 64) {
      const float* rb = rois + (size_t)(m0 + t) * 5;
      const float x1 = rb[1], y1 = rb[2], x2 = rb[3], y2 = rb[4];
      Bsb[t * 5 + 0] = x1; Bsb[t * 5 + 1] = y1;
      Bsb[t * 5 + 2] = x2; Bsb[t * 5 + 3] = y2;
      Bsb[t * 5 + 4] = (x2 - x1 + 1.f) * (y2 - y1 + 1.f);
    }
    __syncthreads();

    floatx4 sc[4];
#pragma unroll
    for (int ct = 0; ct < 4; ++ct) {
      const short8 b0 = *(const short8*)&Kf[(ct * 2 + 0) * 512 + lane * 8];
      const short8 b1 = *(const short8*)&Kf[(ct * 2 + 1) * 512 + lane * 8];
      floatx4 z4 = (floatx4){0.f, 0.f, 0.f, 0.f};
      z4 = MFMA_BF16(qf0, b0, z4);
      z4 = MFMA_BF16(qf1, b1, z4);
      sc[ct] = z4;
    }
#pragma unroll
    for (int ct = 0; ct < 4; ++ct) {
      const int k = ct * 16 + col;
      const float kx1 = Bsb[k * 5 + 0], ky1 = Bsb[k * 5 + 1];
      const float kx2 = Bsb[k * 5 + 2], ky2 = Bsb[k * 5 + 3], ka = Bsb[k * 5 + 4];
#pragma unroll
      for (int r = 0; r < 4; ++r) {
        float iw = fminf(qx2[r], kx2) - fmaxf(qx1[r], kx1) + 1.f;
        float ih = fminf(qy2[r], ky2) - fmaxf(qy1[r], ky1) + 1.f;
        iw = fmaxf(iw, 0.f); ih = fmaxf(ih, 0.f);
        const float inter = iw * ih;
        const float iou = inter * __builtin_amdgcn_rcpf(qar[r] + ka - inter);
        sc[ct][r] = __expf(sc[ct][r] * 0.125f) * (iou + 1e-6f);
      }
    }
#pragma unroll
    for (int r = 0; r < 4; ++r)
      lsum[r] += sc[0][r] + sc[1][r] + sc[2][r] + sc[3][r];
    {
      short* pw = &Pf[w * 1024];
#pragma unroll
      for (int ct = 0; ct < 4; ++ct) {
        const int key = ct * 16 + col;
        const int base = (key >> 5) * 512 + (key & 7);
#pragma unroll
        for (int r = 0; r < 4; ++r) {
          const int dl = (4 * qq + r) + ((key >> 3) & 3) * 16;
          pw[base + dl * 8] = f2bf(sc[ct][r]);
        }
      }
      const short8 pa0 = *(const short8*)&pw[0 * 512 + lane * 8];
      const short8 pa1 = *(const short8*)&pw[1 * 512 + lane * 8];
#pragma unroll
      for (int dt = 0; dt < 4; ++dt) {
        const short8 v0 = *(const short8*)&Vf[(dt * 2 + 0) * 512 + lane * 8];
        const short8 v1 = *(const short8*)&Vf[(dt * 2 + 1) * 512 + lane * 8];
        oc[dt] = MFMA_BF16(pa0, v0, oc[dt]);
        oc[dt] = MFMA_BF16(pa1, v1, oc[dt]);
      }
    }
  }

#pragma unroll
  for (int r = 0; r < 4; ++r) {
    float s = lsum[r];
    s += __shfl_xor(s, 1); s += __shfl_xor(s, 2);
    s += __shfl_xor(s, 4); s += __shfl_xor(s, 8);
    lsum[r] = s;
  }
#pragma unroll
  for (int dt = 0; dt < 4; ++dt) {
    const float bo = bout[g * DH + dt * 16 + col];
#pragma unroll
    for (int r = 0; r < 4; ++r)
      Out[(size_t)(n0 + w * 16 + qq * 4 + r) * CDIM + g * DH + dt * 16 + col] =
          oc[dt][r] / lsum[r] + bo;
  }
}

extern "C" void kernel_launch(void* const* d_in, const int* in_sizes, int n_in,
                              void* d_out, int out_size, void* d_ws, size_t ws_size,
                              hipStream_t stream) {
  const float* in_x = (const float*)d_in[0];
  const float* rois = (const float*)d_in[1];
  const float* W0   = (const float*)d_in[2];
  const float* b0   = (const float*)d_in[3];
  const float* W1   = (const float*)d_in[4];
  const float* b1   = (const float*)d_in[5];
  const float* Wout = (const float*)d_in[6];  // (G,D,C) flat == (C,C) row-major
  const float* bout = (const float*)d_in[7];
  float* out = (float*)d_out;
  char* w8 = (char*)d_ws;

  // ws layout (bytes):
  //   [0,4M)   xin_b  (bf16 in_x)      -> reused as xb (GEMM1 out) after GEMM2
  //   [4,6M)   W0b   [6,8M) W1b   [8,10M) Woutb
  //   [10,14M) zT    (bf16 V^T)
  //   [14,22M) biasb (bf16 iou matrix) -- only if ws allows
  // t0b (GEMM0 out, bf16 4MB) lives in d_out (8MB), fully overwritten by attn.
  short* xin_b = (short*)(w8);
  short* W0b   = (short*)(w8 + (4u << 20));
  short* W1b   = (short*)(w8 + (6u << 20));
  short* Woutb = (short*)(w8 + (8u << 20));
  short* zT    = (short*)(w8 + (10u << 20));
  unsigned short* biasb = (unsigned short*)(w8 + (14u << 20));
  short* xb  = xin_b;
  short* t0b = (short*)d_out;
  const bool useBias = ws_size >= ((size_t)22u << 20);

  convert_kernel<<<2048, 256, 0, stream>>>(in_x, W0, W1, Wout,
                                           xin_b, W0b, W1b, Woutb);
  if (useBias)
    iou_kernel<<<dim3(NROI / 256, NROI), 256, 0, stream>>>(rois, biasb);

  const dim3 gg(CDIM / 64, NROI / 64);  // (16, 32)
  // t0 = relu(in_x) @ W0^T + b0        (relu applied in-register on bf16 A)
  gemm_bf16<<<gg, 256, 0, stream>>>(xin_b, W0b, b0, t0b,
                                    NROI, CDIM, CDIM, 1, 0);
  // zT = (in_x @ Wout^T)^T             (before GEMM1, which overwrites xin_b)
  gemm_bf16<<<gg, 256, 0, stream>>>(xin_b, Woutb, nullptr, zT,
                                    NROI, CDIM, CDIM, 0, 1);
  // xb = relu(t0) @ W1^T + b1
  gemm_bf16<<<gg, 256, 0, stream>>>(t0b, W1b, b1, xb,
                                    NROI, CDIM, CDIM, 1, 0);

  if (useBias)
    attn_bias<<<dim3(NROI / 128, NG), 512, 0, stream>>>(xb, zT, biasb, bout, out);
  else
    attn_inline<<<dim3(NROI / 64, NG), 256, 0, stream>>>(xb, zT, rois, bout, out);
}